// Round 11
// baseline (279.920 us; speedup 1.0000x reference)
//
#include <hip/hip_runtime.h>

#define N_NODES  80000
#define N_EDGES  1280000
#define N_GRAPHS 512
#define DIM      64
#define NCLS     10

#define ETILE    8192
#define NTILE    157      // ceil(N_EDGES / ETILE)
#define NCB      157      // ceil(N_NODES / 512) coarse buckets of 512 nodes
#define CBPAD    160

typedef short short8f __attribute__((ext_vector_type(8)));   // 8 bf16 (4 VGPRs)
typedef float float4f __attribute__((ext_vector_type(4)));   // 4 fp32 acc

static __device__ __forceinline__ unsigned short f2bf(float f) {
    unsigned u = __float_as_uint(f);
    unsigned r = (u + 0x7FFFu + ((u >> 16) & 1u)) >> 16;   // RNE
    return (unsigned short)r;
}
static __device__ __forceinline__ float bf_lo(unsigned v) { return __uint_as_float(v << 16); }
static __device__ __forceinline__ float bf_hi(unsigned v) { return __uint_as_float(v & 0xFFFF0000u); }

// ---------- Pass A: per-tile histogram over coarse buckets (no global atomics)
__global__ __launch_bounds__(256) void k_hist(const int* __restrict__ ei,
                                              int* __restrict__ hmat) {
    __shared__ int hist[NCB];
    int tile = blockIdx.x, t = threadIdx.x;
    for (int i = t; i < NCB; i += 256) hist[i] = 0;
    __syncthreads();
    int base = tile * ETILE;
    int end = base + ETILE; if (end > N_EDGES) end = N_EDGES;
    for (int i = base + t; i < end; i += 256)
        atomicAdd(&hist[ei[N_EDGES + i] >> 9], 1);
    __syncthreads();
    for (int i = t; i < NCB; i += 256) hmat[tile * CBPAD + i] = hist[i];
}

// ---------- Pass B1: per-bucket scan across tiles -> within-bucket offsets
__global__ __launch_bounds__(256) void k_scanT(const int* __restrict__ hmat,
        int* __restrict__ obase, int* __restrict__ btot) {
    __shared__ int sa[256], sb[256];
    int b = blockIdx.x, t = threadIdx.x;
    int v = (t < NTILE) ? hmat[t * CBPAD + b] : 0;
    sa[t] = v; __syncthreads();
    int* sp = sa; int* dp = sb;
    for (int off = 1; off < 256; off <<= 1) {
        dp[t] = sp[t] + ((t >= off) ? sp[t - off] : 0);
        __syncthreads();
        int* tmp = sp; sp = dp; dp = tmp;
    }
    int incl = sp[t];
    if (t < NTILE) obase[t * CBPAD + b] = incl - v;
    if (t == NTILE - 1) btot[b] = incl;
}

// ---------- Pass B2: scan bucket totals -> bucket bases
__global__ __launch_bounds__(256) void k_scanB(const int* __restrict__ btot,
        int* __restrict__ bucketbase, int* __restrict__ rowptr) {
    __shared__ int sa[256], sb[256];
    int t = threadIdx.x;
    int v = (t < NCB) ? btot[t] : 0;
    sa[t] = v; __syncthreads();
    int* sp = sa; int* dp = sb;
    for (int off = 1; off < 256; off <<= 1) {
        dp[t] = sp[t] + ((t >= off) ? sp[t - off] : 0);
        __syncthreads();
        int* tmp = sp; sp = dp; dp = tmp;
    }
    int incl = sp[t];
    if (t < NCB) bucketbase[t] = incl - v;
    if (t == 0) { bucketbase[NCB] = N_EDGES; rowptr[N_NODES] = N_EDGES; }
}

// ---------- Pass C: scatter into bucket-sorted ebuf (deterministic runs)
__global__ __launch_bounds__(256) void k_scatter(const int* __restrict__ ei,
        const int* __restrict__ obase, const int* __restrict__ bucketbase,
        int* __restrict__ ebuf) {
    __shared__ int cur[NCB];
    int tile = blockIdx.x, t = threadIdx.x;
    for (int i = t; i < NCB; i += 256)
        cur[i] = bucketbase[i] + obase[tile * CBPAD + i];
    __syncthreads();
    int base = tile * ETILE;
    int end = base + ETILE; if (end > N_EDGES) end = N_EDGES;
    for (int i = base + t; i < end; i += 256) {
        int s = ei[i], d = ei[N_EDGES + i];
        int p = atomicAdd(&cur[d >> 9], 1);
        ebuf[p] = s | ((d & 511) << 17);   // src:17 bits, local dst:9 bits
    }
}

// ---------- Pass D: per-bucket node-level CSR, all in LDS
__global__ __launch_bounds__(256) void k_csr(const int* __restrict__ ebuf,
        const int* __restrict__ bucketbase, int* __restrict__ rowptr,
        int* __restrict__ col) {
    __shared__ int cnt[512];
    __shared__ int sa[512], sb[512];
    __shared__ int cur[512];
    int b = blockIdx.x, t = threadIdx.x;
    int s = bucketbase[b], e = bucketbase[b + 1];
    cnt[t] = 0; cnt[t + 256] = 0;
    __syncthreads();
    for (int i = s + t; i < e; i += 256) atomicAdd(&cnt[ebuf[i] >> 17], 1);
    __syncthreads();
    sa[t] = cnt[t]; sa[t + 256] = cnt[t + 256];
    __syncthreads();
    int* sp = sa; int* dp = sb;
    for (int off = 1; off < 512; off <<= 1) {
        int i1 = t + 256;
        int v0 = sp[t]  + ((t  >= off) ? sp[t  - off] : 0);
        int v1 = sp[i1] + ((i1 >= off) ? sp[i1 - off] : 0);
        __syncthreads();
        dp[t] = v0; dp[i1] = v1;
        __syncthreads();
        int* tmp = sp; sp = dp; dp = tmp;
    }
    int node0 = b * 512;
    int base0 = s + sp[t] - cnt[t];
    int base1 = s + sp[t + 256] - cnt[t + 256];
    cur[t] = base0; cur[t + 256] = base1;
    if (node0 + t < N_NODES)       rowptr[node0 + t] = base0;
    if (node0 + t + 256 < N_NODES) rowptr[node0 + t + 256] = base1;
    __syncthreads();
    for (int i = s + t; i < e; i += 256) {
        int pk = ebuf[i];
        int p = atomicAdd(&cur[pk >> 17], 1);
        col[p] = pk & 0x1FFFF;
    }
}

// ---------- prep: cast x -> bf16 (blocks 0..4999) + pack W1/W2 into MFMA
// B-frag order bf16 (blocks 5000..5063). wf[l][nt][ks][lane][j]
__global__ __launch_bounds__(256) void k_prep2(const float* __restrict__ x,
        const float* __restrict__ wr1, const float* __restrict__ wo1,
        const float* __restrict__ wr2, const float* __restrict__ wo2,
        unsigned short* __restrict__ xb, unsigned short* __restrict__ wf) {
    int bid = blockIdx.x, t = threadIdx.x;
    if (bid < 5000) {
        int i = bid * 256 + t;                  // N_NODES*16 float4s
        float4 v = ((const float4*)x)[i];
        ushort4 o;
        o.x = f2bf(v.x); o.y = f2bf(v.y); o.z = f2bf(v.z); o.w = f2bf(v.w);
        ((ushort4*)xb)[i] = o;
    } else {
        int idx = (bid - 5000) * 256 + t;       // < 2*8192
        int j = idx & 7, lane = (idx >> 3) & 63;
        int ks = (idx >> 9) & 3, nt = (idx >> 11) & 3, l = idx >> 13;
        int k = ks * 32 + ((lane >> 4) & 3) * 8 + j;
        int n = nt * 16 + (lane & 15);
        const float* wr = (l == 0) ? wr1 : wr2;
        const float* wo = (l == 0) ? wo1 : wo2;
        float val = (k < 64) ? wr[n * 64 + k] : wo[n * 64 + (k - 64)];
        wf[idx] = f2bf(val);
    }
}

// ---------- aggregation over bf16 rows: 2 nodes/wave, lane=dword
// main loop unroll 16 (32 rows in flight per wave), tail 4 + scalar
__global__ __launch_bounds__(256) void k_gather_bf(const unsigned short* __restrict__ Xbf,
        const int* __restrict__ rowptr, const int* __restrict__ col,
        unsigned short* __restrict__ agg) {
    const unsigned* Xu = (const unsigned*)Xbf;
    int t = threadIdx.x, w = t >> 6, lane = t & 63;
    int g = lane >> 5, c = lane & 31;
    int node = blockIdx.x * 8 + w * 2 + g;
    int start = rowptr[node], end = rowptr[node + 1];
    float alo = 0.f, ahi = 0.f;
    int e = start;
    for (; e + 16 <= end; e += 16) {
        unsigned v[16];
#pragma unroll
        for (int j = 0; j < 16; ++j)
            v[j] = Xu[(size_t)col[e + j] * 32 + c];
#pragma unroll
        for (int j = 0; j < 16; ++j) { alo += bf_lo(v[j]); ahi += bf_hi(v[j]); }
    }
    for (; e + 4 <= end; e += 4) {
        unsigned v0 = Xu[(size_t)col[e]     * 32 + c];
        unsigned v1 = Xu[(size_t)col[e + 1] * 32 + c];
        unsigned v2 = Xu[(size_t)col[e + 2] * 32 + c];
        unsigned v3 = Xu[(size_t)col[e + 3] * 32 + c];
        alo += (bf_lo(v0) + bf_lo(v1)) + (bf_lo(v2) + bf_lo(v3));
        ahi += (bf_hi(v0) + bf_hi(v1)) + (bf_hi(v2) + bf_hi(v3));
    }
    for (; e < end; ++e) {
        unsigned v = Xu[(size_t)col[e] * 32 + c];
        alo += bf_lo(v); ahi += bf_hi(v);
    }
    unsigned o = (unsigned)f2bf(alo) | ((unsigned)f2bf(ahi) << 16);
    ((unsigned*)agg)[(size_t)node * 32 + c] = o;
}

// ---------- MFMA linear: out = act([agg|x] @ W + b), bf16 in/out, no LDS
__global__ __launch_bounds__(256) void k_linear_mfma(
        const unsigned short* __restrict__ aggb, const unsigned short* __restrict__ xb,
        const unsigned short* __restrict__ wf, const float* __restrict__ bias,
        unsigned short* __restrict__ out, int relu) {
    int t = threadIdx.x, w = t >> 6, lane = t & 63;
    int quad = lane >> 4, l15 = lane & 15;
    int mbase = blockIdx.x * 64 + w * 16;
    size_t arow = (size_t)(mbase + l15) * 64;
    short8f a0 = *(const short8f*)(aggb + arow + quad * 8);
    short8f a1 = *(const short8f*)(aggb + arow + 32 + quad * 8);
    short8f a2 = *(const short8f*)(xb   + arow + quad * 8);
    short8f a3 = *(const short8f*)(xb   + arow + 32 + quad * 8);
    int orow = mbase + quad * 4;
#pragma unroll
    for (int nt = 0; nt < 4; ++nt) {
        const unsigned short* wp = wf + ((size_t)(nt * 4) * 64 + lane) * 8;
        short8f b0 = *(const short8f*)(wp);
        short8f b1 = *(const short8f*)(wp + 64 * 8);
        short8f b2 = *(const short8f*)(wp + 128 * 8);
        short8f b3 = *(const short8f*)(wp + 192 * 8);
        float4f acc = {0.f, 0.f, 0.f, 0.f};
        acc = __builtin_amdgcn_mfma_f32_16x16x32_bf16(a0, b0, acc, 0, 0, 0);
        acc = __builtin_amdgcn_mfma_f32_16x16x32_bf16(a1, b1, acc, 0, 0, 0);
        acc = __builtin_amdgcn_mfma_f32_16x16x32_bf16(a2, b2, acc, 0, 0, 0);
        acc = __builtin_amdgcn_mfma_f32_16x16x32_bf16(a3, b3, acc, 0, 0, 0);
        float bi = bias[nt * 16 + l15];
#pragma unroll
        for (int r = 0; r < 4; ++r) {
            float v = acc[r] + bi;
            if (relu) v = fmaxf(v, 0.f);
            out[(size_t)(orow + r) * 64 + nt * 16 + l15] = f2bf(v);
        }
    }
}

static __device__ __forceinline__ int lowerb(const int* a, int n, int key) {
    int lo = 0, hi = n;
    while (lo < hi) { int mid = (lo + hi) >> 1; if (a[mid] < key) lo = mid + 1; else hi = mid; }
    return lo;
}

// ---------- layer-3 collapse, stage 1: per-graph sums
// S[g][0..63]  = sum over edges with dst in g of h2[src]   (graph's edges are
//                contiguous in col because nodes are sorted by graph)
// S[g][64..127]= sum over nodes in g of h2[i]
__global__ __launch_bounds__(256) void k_gsum(const unsigned short* __restrict__ h2,
        const int* __restrict__ rowptr, const int* __restrict__ col,
        const int* __restrict__ batch, float* __restrict__ S) {
    __shared__ float red1[8][64];
    __shared__ float red2[8][64];
    const unsigned* Xu = (const unsigned*)h2;
    int g = blockIdx.x, t = threadIdx.x;
    int hw = t >> 5, c = t & 31;
    int ns = lowerb(batch, N_NODES, g);
    int ne = lowerb(batch, N_NODES, g + 1);
    int es = rowptr[ns], ee = rowptr[ne];
    float alo = 0.f, ahi = 0.f;
    int nfull = (ee - es) >> 7;            // full 128-edge superblocks
    int e0 = es + hw * 16;
    for (int b = 0; b < nfull; ++b, e0 += 128) {
        unsigned v[16];
#pragma unroll
        for (int j = 0; j < 16; ++j)
            v[j] = Xu[(size_t)col[e0 + j] * 32 + c];
#pragma unroll
        for (int j = 0; j < 16; ++j) { alo += bf_lo(v[j]); ahi += bf_hi(v[j]); }
    }
    for (int e = es + nfull * 128 + hw; e < ee; e += 8) {
        unsigned v = Xu[(size_t)col[e] * 32 + c];
        alo += bf_lo(v); ahi += bf_hi(v);
    }
    float blo = 0.f, bhi = 0.f;
    for (int i = ns + hw; i < ne; i += 8) {
        unsigned v = Xu[(size_t)i * 32 + c];
        blo += bf_lo(v); bhi += bf_hi(v);
    }
    red1[hw][2 * c] = alo; red1[hw][2 * c + 1] = ahi;
    red2[hw][2 * c] = blo; red2[hw][2 * c + 1] = bhi;
    __syncthreads();
    if (t < 64) {
        float v = 0.f;
#pragma unroll
        for (int s = 0; s < 8; ++s) v += red1[s][t];
        S[g * 128 + t] = v;
    } else if (t < 128) {
        float v = 0.f;
#pragma unroll
        for (int s = 0; s < 8; ++s) v += red2[s][t - 64];
        S[g * 128 + 64 + (t - 64)] = v;
    }
}

// ---------- layer-3 collapse, stage 2: pooled = S1/c @ Wr3^T + b3 + S2/c @ Wo3^T
// then out = pooled @ wlin^T + blin   (all fp32)
__global__ __launch_bounds__(64) void k_head2(const float* __restrict__ S,
        const int* __restrict__ batch,
        const float* __restrict__ wr3, const float* __restrict__ wo3,
        const float* __restrict__ b3,
        const float* __restrict__ wlin, const float* __restrict__ blin,
        float* __restrict__ out) {
    __shared__ float s1[64], s2[64], pl[64];
    int g = blockIdx.x, t = threadIdx.x;
    int ns = lowerb(batch, N_NODES, g);
    int ne = lowerb(batch, N_NODES, g + 1);
    float inv = 1.f / (float)((ne > ns) ? (ne - ns) : 1);
    s1[t] = S[g * 128 + t] * inv;
    s2[t] = S[g * 128 + 64 + t] * inv;
    __syncthreads();
    float acc = b3[t];
    for (int k = 0; k < 64; ++k)
        acc += s1[k] * wr3[t * 64 + k] + s2[k] * wo3[t * 64 + k];
    pl[t] = acc;
    __syncthreads();
    float myout = 0.f;
    for (int cls = 0; cls < NCLS; ++cls) {
        float vv = pl[t] * wlin[cls * 64 + t];
        for (int off = 32; off > 0; off >>= 1) vv += __shfl_xor(vv, off);
        if (t == cls) myout = vv + blin[cls];
    }
    if (t < NCLS) out[g * NCLS + t] = myout;
}

extern "C" void kernel_launch(void* const* d_in, const int* in_sizes, int n_in,
                              void* d_out, int out_size, void* d_ws, size_t ws_size,
                              hipStream_t stream) {
    const float* x     = (const float*)d_in[0];
    const int*   ei    = (const int*)d_in[1];
    const int*   batch = (const int*)d_in[2];
    const float* wr1 = (const float*)d_in[3];
    const float* b1  = (const float*)d_in[4];
    const float* wo1 = (const float*)d_in[5];
    const float* wr2 = (const float*)d_in[6];
    const float* b2  = (const float*)d_in[7];
    const float* wo2 = (const float*)d_in[8];
    const float* wr3 = (const float*)d_in[9];
    const float* b3  = (const float*)d_in[10];
    const float* wo3 = (const float*)d_in[11];
    const float* wlin = (const float*)d_in[12];
    const float* blin = (const float*)d_in[13];
    float* out = (float*)d_out;

    char* p = (char*)d_ws;
    auto alloc = [&](size_t bytes) { char* r = p; p += (bytes + 255) & ~(size_t)255; return r; };
    int*   rowptr  = (int*)alloc((N_NODES + 1) * sizeof(int));
    int*   hmat    = (int*)alloc((size_t)NTILE * CBPAD * sizeof(int));
    int*   obase   = (int*)alloc((size_t)NTILE * CBPAD * sizeof(int));
    int*   btot    = (int*)alloc(CBPAD * sizeof(int));
    int*   bucketbase = (int*)alloc((NCB + 1) * sizeof(int));
    int*   ebuf    = (int*)alloc((size_t)N_EDGES * sizeof(int));
    int*   col     = (int*)alloc((size_t)N_EDGES * sizeof(int));
    unsigned short* wf  = (unsigned short*)alloc(2 * 8192 * sizeof(unsigned short));
    unsigned short* xbf = (unsigned short*)alloc((size_t)N_NODES * 64 * 2);
    unsigned short* agg = (unsigned short*)alloc((size_t)N_NODES * 64 * 2);
    unsigned short* hA  = (unsigned short*)alloc((size_t)N_NODES * 64 * 2);
    unsigned short* hB  = (unsigned short*)alloc((size_t)N_NODES * 64 * 2);
    float* S       = (float*)alloc((size_t)N_GRAPHS * 128 * sizeof(float));

    // CSR build: deterministic two-level counting sort, zero global atomics
    k_hist   <<<NTILE, 256, 0, stream>>>(ei, hmat);
    k_scanT  <<<NCB,   256, 0, stream>>>(hmat, obase, btot);
    k_scanB  <<<1,     256, 0, stream>>>(btot, bucketbase, rowptr);
    k_scatter<<<NTILE, 256, 0, stream>>>(ei, obase, bucketbase, ebuf);
    k_csr    <<<NCB,   256, 0, stream>>>(ebuf, bucketbase, rowptr, col);
    k_prep2  <<<5064,  256, 0, stream>>>(x, wr1, wo1, wr2, wo2, xbf, wf);

    // layer 1
    k_gather_bf  <<<N_NODES / 8,  256, 0, stream>>>(xbf, rowptr, col, agg);
    k_linear_mfma<<<N_NODES / 64, 256, 0, stream>>>(agg, xbf, wf,        b1, hA, 1);
    // layer 2
    k_gather_bf  <<<N_NODES / 8,  256, 0, stream>>>(hA, rowptr, col, agg);
    k_linear_mfma<<<N_NODES / 64, 256, 0, stream>>>(agg, hA, wf + 8192,  b2, hB, 1);
    // layer 3 + pool collapsed: per-graph sums, then tiny fp32 head
    k_gsum <<<N_GRAPHS, 256, 0, stream>>>(hB, rowptr, col, batch, S);
    k_head2<<<N_GRAPHS, 64,  0, stream>>>(S, batch, wr3, wo3, b3, wlin, blin, out);
}

// Round 12
// 266.085 us; speedup vs baseline: 1.0520x; 1.0520x over previous
//
#include <hip/hip_runtime.h>

#define N_NODES  80000
#define N_EDGES  1280000
#define N_GRAPHS 512
#define DIM      64
#define NCLS     10

#define ETILE    8192
#define NTILE    157      // ceil(N_EDGES / ETILE)
#define NCB      157      // ceil(N_NODES / 512) coarse buckets of 512 nodes
#define CBPAD    160

typedef short short8f __attribute__((ext_vector_type(8)));   // 8 bf16 (4 VGPRs)
typedef float float4f __attribute__((ext_vector_type(4)));   // 4 fp32 acc

static __device__ __forceinline__ unsigned short f2bf(float f) {
    unsigned u = __float_as_uint(f);
    unsigned r = (u + 0x7FFFu + ((u >> 16) & 1u)) >> 16;   // RNE
    return (unsigned short)r;
}
static __device__ __forceinline__ float bf_lo(unsigned v) { return __uint_as_float(v << 16); }
static __device__ __forceinline__ float bf_hi(unsigned v) { return __uint_as_float(v & 0xFFFF0000u); }

// ---------- Pass A: per-tile histogram over coarse buckets (no global atomics)
__global__ __launch_bounds__(256) void k_hist(const int* __restrict__ ei,
                                              int* __restrict__ hmat) {
    __shared__ int hist[NCB];
    int tile = blockIdx.x, t = threadIdx.x;
    for (int i = t; i < NCB; i += 256) hist[i] = 0;
    __syncthreads();
    int base = tile * ETILE;
    int end = base + ETILE; if (end > N_EDGES) end = N_EDGES;
    for (int i = base + t; i < end; i += 256)
        atomicAdd(&hist[ei[N_EDGES + i] >> 9], 1);
    __syncthreads();
    for (int i = t; i < NCB; i += 256) hmat[tile * CBPAD + i] = hist[i];
}

// ---------- Pass B1: per-bucket scan across tiles -> within-bucket offsets
__global__ __launch_bounds__(256) void k_scanT(const int* __restrict__ hmat,
        int* __restrict__ obase, int* __restrict__ btot) {
    __shared__ int sa[256], sb[256];
    int b = blockIdx.x, t = threadIdx.x;
    int v = (t < NTILE) ? hmat[t * CBPAD + b] : 0;
    sa[t] = v; __syncthreads();
    int* sp = sa; int* dp = sb;
    for (int off = 1; off < 256; off <<= 1) {
        dp[t] = sp[t] + ((t >= off) ? sp[t - off] : 0);
        __syncthreads();
        int* tmp = sp; sp = dp; dp = tmp;
    }
    int incl = sp[t];
    if (t < NTILE) obase[t * CBPAD + b] = incl - v;
    if (t == NTILE - 1) btot[b] = incl;
}

// ---------- Pass B2: scan bucket totals -> bucket bases
__global__ __launch_bounds__(256) void k_scanB(const int* __restrict__ btot,
        int* __restrict__ bucketbase, int* __restrict__ rowptr) {
    __shared__ int sa[256], sb[256];
    int t = threadIdx.x;
    int v = (t < NCB) ? btot[t] : 0;
    sa[t] = v; __syncthreads();
    int* sp = sa; int* dp = sb;
    for (int off = 1; off < 256; off <<= 1) {
        dp[t] = sp[t] + ((t >= off) ? sp[t - off] : 0);
        __syncthreads();
        int* tmp = sp; sp = dp; dp = tmp;
    }
    int incl = sp[t];
    if (t < NCB) bucketbase[t] = incl - v;
    if (t == 0) { bucketbase[NCB] = N_EDGES; rowptr[N_NODES] = N_EDGES; }
}

// ---------- Pass C: scatter into bucket-sorted ebuf (deterministic runs)
__global__ __launch_bounds__(256) void k_scatter(const int* __restrict__ ei,
        const int* __restrict__ obase, const int* __restrict__ bucketbase,
        int* __restrict__ ebuf) {
    __shared__ int cur[NCB];
    int tile = blockIdx.x, t = threadIdx.x;
    for (int i = t; i < NCB; i += 256)
        cur[i] = bucketbase[i] + obase[tile * CBPAD + i];
    __syncthreads();
    int base = tile * ETILE;
    int end = base + ETILE; if (end > N_EDGES) end = N_EDGES;
    for (int i = base + t; i < end; i += 256) {
        int s = ei[i], d = ei[N_EDGES + i];
        int p = atomicAdd(&cur[d >> 9], 1);
        ebuf[p] = s | ((d & 511) << 17);   // src:17 bits, local dst:9 bits
    }
}

// ---------- Pass D: per-bucket node-level CSR, all in LDS
__global__ __launch_bounds__(256) void k_csr(const int* __restrict__ ebuf,
        const int* __restrict__ bucketbase, int* __restrict__ rowptr,
        int* __restrict__ col) {
    __shared__ int cnt[512];
    __shared__ int sa[512], sb[512];
    __shared__ int cur[512];
    int b = blockIdx.x, t = threadIdx.x;
    int s = bucketbase[b], e = bucketbase[b + 1];
    cnt[t] = 0; cnt[t + 256] = 0;
    __syncthreads();
    for (int i = s + t; i < e; i += 256) atomicAdd(&cnt[ebuf[i] >> 17], 1);
    __syncthreads();
    sa[t] = cnt[t]; sa[t + 256] = cnt[t + 256];
    __syncthreads();
    int* sp = sa; int* dp = sb;
    for (int off = 1; off < 512; off <<= 1) {
        int i1 = t + 256;
        int v0 = sp[t]  + ((t  >= off) ? sp[t  - off] : 0);
        int v1 = sp[i1] + ((i1 >= off) ? sp[i1 - off] : 0);
        __syncthreads();
        dp[t] = v0; dp[i1] = v1;
        __syncthreads();
        int* tmp = sp; sp = dp; dp = tmp;
    }
    int node0 = b * 512;
    int base0 = s + sp[t] - cnt[t];
    int base1 = s + sp[t + 256] - cnt[t + 256];
    cur[t] = base0; cur[t + 256] = base1;
    if (node0 + t < N_NODES)       rowptr[node0 + t] = base0;
    if (node0 + t + 256 < N_NODES) rowptr[node0 + t + 256] = base1;
    __syncthreads();
    for (int i = s + t; i < e; i += 256) {
        int pk = ebuf[i];
        int p = atomicAdd(&cur[pk >> 17], 1);
        col[p] = pk & 0x1FFFF;
    }
}

// ---------- prep: cast x -> bf16 (blocks 0..4999) + pack W1/W2 into MFMA
// B-frag order bf16 (blocks 5000..5063). wf[l][nt][ks][lane][j]
__global__ __launch_bounds__(256) void k_prep2(const float* __restrict__ x,
        const float* __restrict__ wr1, const float* __restrict__ wo1,
        const float* __restrict__ wr2, const float* __restrict__ wo2,
        unsigned short* __restrict__ xb, unsigned short* __restrict__ wf) {
    int bid = blockIdx.x, t = threadIdx.x;
    if (bid < 5000) {
        int i = bid * 256 + t;                  // N_NODES*16 float4s
        float4 v = ((const float4*)x)[i];
        ushort4 o;
        o.x = f2bf(v.x); o.y = f2bf(v.y); o.z = f2bf(v.z); o.w = f2bf(v.w);
        ((ushort4*)xb)[i] = o;
    } else {
        int idx = (bid - 5000) * 256 + t;       // < 2*8192
        int j = idx & 7, lane = (idx >> 3) & 63;
        int ks = (idx >> 9) & 3, nt = (idx >> 11) & 3, l = idx >> 13;
        int k = ks * 32 + ((lane >> 4) & 3) * 8 + j;
        int n = nt * 16 + (lane & 15);
        const float* wr = (l == 0) ? wr1 : wr2;
        const float* wo = (l == 0) ? wo1 : wo2;
        float val = (k < 64) ? wr[n * 64 + k] : wo[n * 64 + (k - 64)];
        wf[idx] = f2bf(val);
    }
}

// ---------- aggregation, 16B/lane: wave = 1 node; lane = (edge-slot e, chunk c)
// 8 edges x 128B per issue; shuffle-reduce over e; lanes e==0 store the row
__global__ __launch_bounds__(256) void k_gather4(const unsigned short* __restrict__ Xbf,
        const int* __restrict__ rowptr, const int* __restrict__ col,
        unsigned short* __restrict__ agg) {
    const uint4* Xq = (const uint4*)Xbf;
    int t = threadIdx.x, w = t >> 6, lane = t & 63;
    int e = lane >> 3, c = lane & 7;
    int node = blockIdx.x * 4 + w;
    int start = rowptr[node], end = rowptr[node + 1];
    float acc[8] = {0.f, 0.f, 0.f, 0.f, 0.f, 0.f, 0.f, 0.f};
    int base = start;
    for (; base + 16 <= end; base += 16) {       // 2 uint4 loads in flight
        int i0 = col[base + e];
        int i1 = col[base + 8 + e];
        uint4 v0 = Xq[(size_t)i0 * 8 + c];
        uint4 v1 = Xq[(size_t)i1 * 8 + c];
        acc[0] += bf_lo(v0.x) + bf_lo(v1.x); acc[1] += bf_hi(v0.x) + bf_hi(v1.x);
        acc[2] += bf_lo(v0.y) + bf_lo(v1.y); acc[3] += bf_hi(v0.y) + bf_hi(v1.y);
        acc[4] += bf_lo(v0.z) + bf_lo(v1.z); acc[5] += bf_hi(v0.z) + bf_hi(v1.z);
        acc[6] += bf_lo(v0.w) + bf_lo(v1.w); acc[7] += bf_hi(v0.w) + bf_hi(v1.w);
    }
    for (; base + 8 <= end; base += 8) {
        int i0 = col[base + e];
        uint4 v0 = Xq[(size_t)i0 * 8 + c];
        acc[0] += bf_lo(v0.x); acc[1] += bf_hi(v0.x);
        acc[2] += bf_lo(v0.y); acc[3] += bf_hi(v0.y);
        acc[4] += bf_lo(v0.z); acc[5] += bf_hi(v0.z);
        acc[6] += bf_lo(v0.w); acc[7] += bf_hi(v0.w);
    }
    int r = end - base;
    if (e < r) {
        int i0 = col[base + e];
        uint4 v0 = Xq[(size_t)i0 * 8 + c];
        acc[0] += bf_lo(v0.x); acc[1] += bf_hi(v0.x);
        acc[2] += bf_lo(v0.y); acc[3] += bf_hi(v0.y);
        acc[4] += bf_lo(v0.z); acc[5] += bf_hi(v0.z);
        acc[6] += bf_lo(v0.w); acc[7] += bf_hi(v0.w);
    }
#pragma unroll
    for (int off = 8; off < 64; off <<= 1) {
#pragma unroll
        for (int j = 0; j < 8; ++j) acc[j] += __shfl_xor(acc[j], off);
    }
    if (e == 0) {
        uint4 o;
        o.x = (unsigned)f2bf(acc[0]) | ((unsigned)f2bf(acc[1]) << 16);
        o.y = (unsigned)f2bf(acc[2]) | ((unsigned)f2bf(acc[3]) << 16);
        o.z = (unsigned)f2bf(acc[4]) | ((unsigned)f2bf(acc[5]) << 16);
        o.w = (unsigned)f2bf(acc[6]) | ((unsigned)f2bf(acc[7]) << 16);
        ((uint4*)agg)[(size_t)node * 8 + c] = o;
    }
}

// ---------- MFMA linear: out = act([agg|x] @ W + b), bf16 in/out, no LDS
__global__ __launch_bounds__(256) void k_linear_mfma(
        const unsigned short* __restrict__ aggb, const unsigned short* __restrict__ xb,
        const unsigned short* __restrict__ wf, const float* __restrict__ bias,
        unsigned short* __restrict__ out, int relu) {
    int t = threadIdx.x, w = t >> 6, lane = t & 63;
    int quad = lane >> 4, l15 = lane & 15;
    int mbase = blockIdx.x * 64 + w * 16;
    size_t arow = (size_t)(mbase + l15) * 64;
    short8f a0 = *(const short8f*)(aggb + arow + quad * 8);
    short8f a1 = *(const short8f*)(aggb + arow + 32 + quad * 8);
    short8f a2 = *(const short8f*)(xb   + arow + quad * 8);
    short8f a3 = *(const short8f*)(xb   + arow + 32 + quad * 8);
    int orow = mbase + quad * 4;
#pragma unroll
    for (int nt = 0; nt < 4; ++nt) {
        const unsigned short* wp = wf + ((size_t)(nt * 4) * 64 + lane) * 8;
        short8f b0 = *(const short8f*)(wp);
        short8f b1 = *(const short8f*)(wp + 64 * 8);
        short8f b2 = *(const short8f*)(wp + 128 * 8);
        short8f b3 = *(const short8f*)(wp + 192 * 8);
        float4f acc = {0.f, 0.f, 0.f, 0.f};
        acc = __builtin_amdgcn_mfma_f32_16x16x32_bf16(a0, b0, acc, 0, 0, 0);
        acc = __builtin_amdgcn_mfma_f32_16x16x32_bf16(a1, b1, acc, 0, 0, 0);
        acc = __builtin_amdgcn_mfma_f32_16x16x32_bf16(a2, b2, acc, 0, 0, 0);
        acc = __builtin_amdgcn_mfma_f32_16x16x32_bf16(a3, b3, acc, 0, 0, 0);
        float bi = bias[nt * 16 + l15];
#pragma unroll
        for (int r = 0; r < 4; ++r) {
            float v = acc[r] + bi;
            if (relu) v = fmaxf(v, 0.f);
            out[(size_t)(orow + r) * 64 + nt * 16 + l15] = f2bf(v);
        }
    }
}

static __device__ __forceinline__ int lowerb(const int* a, int n, int key) {
    int lo = 0, hi = n;
    while (lo < hi) { int mid = (lo + hi) >> 1; if (a[mid] < key) lo = mid + 1; else hi = mid; }
    return lo;
}

// ---------- layer-3 collapse, stage 1: per-graph partial sums, 4 parts/graph
// part p covers node range [a_p, a_{p+1}) of graph g; its edges are the
// contiguous run [rowptr[a_p], rowptr[a_{p+1}]) because col is node-major.
__global__ __launch_bounds__(256) void k_gsum(const unsigned short* __restrict__ h2,
        const int* __restrict__ rowptr, const int* __restrict__ col,
        const int* __restrict__ batch, float* __restrict__ S4) {
    __shared__ float red1[8][64];
    __shared__ float red2[8][64];
    const unsigned* Xu = (const unsigned*)h2;
    int g = blockIdx.x >> 2, part = blockIdx.x & 3;
    int t = threadIdx.x;
    int hw = t >> 5, c = t & 31;
    int ns = lowerb(batch, N_NODES, g);
    int ne = lowerb(batch, N_NODES, g + 1);
    int a0 = ns + (int)(((long long)(ne - ns) * part) >> 2);
    int a1 = ns + (int)(((long long)(ne - ns) * (part + 1)) >> 2);
    int es = rowptr[a0], ee = rowptr[a1];
    float alo = 0.f, ahi = 0.f;
    int nfull = (ee - es) >> 7;            // full 128-edge superblocks
    int e0 = es + hw * 16;
    for (int b = 0; b < nfull; ++b, e0 += 128) {
        unsigned v[16];
#pragma unroll
        for (int j = 0; j < 16; ++j)
            v[j] = Xu[(size_t)col[e0 + j] * 32 + c];
#pragma unroll
        for (int j = 0; j < 16; ++j) { alo += bf_lo(v[j]); ahi += bf_hi(v[j]); }
    }
    for (int e = es + nfull * 128 + hw; e < ee; e += 8) {
        unsigned v = Xu[(size_t)col[e] * 32 + c];
        alo += bf_lo(v); ahi += bf_hi(v);
    }
    float blo = 0.f, bhi = 0.f;
    for (int i = a0 + hw; i < a1; i += 8) {
        unsigned v = Xu[(size_t)i * 32 + c];
        blo += bf_lo(v); bhi += bf_hi(v);
    }
    red1[hw][2 * c] = alo; red1[hw][2 * c + 1] = ahi;
    red2[hw][2 * c] = blo; red2[hw][2 * c + 1] = bhi;
    __syncthreads();
    if (t < 64) {
        float v = 0.f;
#pragma unroll
        for (int s = 0; s < 8; ++s) v += red1[s][t];
        S4[(size_t)blockIdx.x * 128 + t] = v;
    } else if (t < 128) {
        float v = 0.f;
#pragma unroll
        for (int s = 0; s < 8; ++s) v += red2[s][t - 64];
        S4[(size_t)blockIdx.x * 128 + 64 + (t - 64)] = v;
    }
}

// ---------- layer-3 collapse, stage 2: pooled = S1/c @ Wr3^T + b3 + S2/c @ Wo3^T
// then out = pooled @ wlin^T + blin   (all fp32)
__global__ __launch_bounds__(64) void k_head2(const float* __restrict__ S4,
        const int* __restrict__ batch,
        const float* __restrict__ wr3, const float* __restrict__ wo3,
        const float* __restrict__ b3,
        const float* __restrict__ wlin, const float* __restrict__ blin,
        float* __restrict__ out) {
    __shared__ float s1[64], s2[64], pl[64];
    int g = blockIdx.x, t = threadIdx.x;
    int ns = lowerb(batch, N_NODES, g);
    int ne = lowerb(batch, N_NODES, g + 1);
    float inv = 1.f / (float)((ne > ns) ? (ne - ns) : 1);
    const float* Sg = S4 + (size_t)g * 4 * 128;
    s1[t] = (Sg[t]       + Sg[128 + t]       + Sg[256 + t]       + Sg[384 + t]) * inv;
    s2[t] = (Sg[64 + t]  + Sg[192 + t]       + Sg[320 + t]       + Sg[448 + t]) * inv;
    __syncthreads();
    float acc = b3[t];
    for (int k = 0; k < 64; ++k)
        acc += s1[k] * wr3[t * 64 + k] + s2[k] * wo3[t * 64 + k];
    pl[t] = acc;
    __syncthreads();
    float myout = 0.f;
    for (int cls = 0; cls < NCLS; ++cls) {
        float vv = pl[t] * wlin[cls * 64 + t];
        for (int off = 32; off > 0; off >>= 1) vv += __shfl_xor(vv, off);
        if (t == cls) myout = vv + blin[cls];
    }
    if (t < NCLS) out[g * NCLS + t] = myout;
}

extern "C" void kernel_launch(void* const* d_in, const int* in_sizes, int n_in,
                              void* d_out, int out_size, void* d_ws, size_t ws_size,
                              hipStream_t stream) {
    const float* x     = (const float*)d_in[0];
    const int*   ei    = (const int*)d_in[1];
    const int*   batch = (const int*)d_in[2];
    const float* wr1 = (const float*)d_in[3];
    const float* b1  = (const float*)d_in[4];
    const float* wo1 = (const float*)d_in[5];
    const float* wr2 = (const float*)d_in[6];
    const float* b2  = (const float*)d_in[7];
    const float* wo2 = (const float*)d_in[8];
    const float* wr3 = (const float*)d_in[9];
    const float* b3  = (const float*)d_in[10];
    const float* wo3 = (const float*)d_in[11];
    const float* wlin = (const float*)d_in[12];
    const float* blin = (const float*)d_in[13];
    float* out = (float*)d_out;

    char* p = (char*)d_ws;
    auto alloc = [&](size_t bytes) { char* r = p; p += (bytes + 255) & ~(size_t)255; return r; };
    int*   rowptr  = (int*)alloc((N_NODES + 1) * sizeof(int));
    int*   hmat    = (int*)alloc((size_t)NTILE * CBPAD * sizeof(int));
    int*   obase   = (int*)alloc((size_t)NTILE * CBPAD * sizeof(int));
    int*   btot    = (int*)alloc(CBPAD * sizeof(int));
    int*   bucketbase = (int*)alloc((NCB + 1) * sizeof(int));
    int*   ebuf    = (int*)alloc((size_t)N_EDGES * sizeof(int));
    int*   col     = (int*)alloc((size_t)N_EDGES * sizeof(int));
    unsigned short* wf  = (unsigned short*)alloc(2 * 8192 * sizeof(unsigned short));
    unsigned short* xbf = (unsigned short*)alloc((size_t)N_NODES * 64 * 2);
    unsigned short* agg = (unsigned short*)alloc((size_t)N_NODES * 64 * 2);
    unsigned short* hA  = (unsigned short*)alloc((size_t)N_NODES * 64 * 2);
    unsigned short* hB  = (unsigned short*)alloc((size_t)N_NODES * 64 * 2);
    float* S4      = (float*)alloc((size_t)N_GRAPHS * 4 * 128 * sizeof(float));

    // CSR build: deterministic two-level counting sort, zero global atomics
    k_hist   <<<NTILE, 256, 0, stream>>>(ei, hmat);
    k_scanT  <<<NCB,   256, 0, stream>>>(hmat, obase, btot);
    k_scanB  <<<1,     256, 0, stream>>>(btot, bucketbase, rowptr);
    k_scatter<<<NTILE, 256, 0, stream>>>(ei, obase, bucketbase, ebuf);
    k_csr    <<<NCB,   256, 0, stream>>>(ebuf, bucketbase, rowptr, col);
    k_prep2  <<<5064,  256, 0, stream>>>(x, wr1, wo1, wr2, wo2, xbf, wf);

    // layer 1
    k_gather4    <<<N_NODES / 4,  256, 0, stream>>>(xbf, rowptr, col, agg);
    k_linear_mfma<<<N_NODES / 64, 256, 0, stream>>>(agg, xbf, wf,        b1, hA, 1);
    // layer 2
    k_gather4    <<<N_NODES / 4,  256, 0, stream>>>(hA, rowptr, col, agg);
    k_linear_mfma<<<N_NODES / 64, 256, 0, stream>>>(agg, hA, wf + 8192,  b2, hB, 1);
    // layer 3 + pool collapsed: per-graph partial sums (4 blocks/graph), tiny head
    k_gsum <<<N_GRAPHS * 4, 256, 0, stream>>>(hB, rowptr, col, batch, S4);
    k_head2<<<N_GRAPHS,     64,  0, stream>>>(S4, batch, wr3, wo3, b3, wlin, blin, out);
}